// Round 1
// baseline (664.521 us; speedup 1.0000x reference)
//
#include <hip/hip_runtime.h>
#include <hip/hip_bf16.h>

#define NNODE 100000
#define NEDGE 1600000

typedef __attribute__((ext_vector_type(8))) short bf16x8;
typedef __attribute__((ext_vector_type(4))) float f32x4;

__device__ __forceinline__ unsigned short f2bf(float f){
  unsigned u = __float_as_uint(f);
  u += 0x7fffu + ((u >> 16) & 1u);
  return (unsigned short)(u >> 16);
}
__device__ __forceinline__ unsigned pk2(float a, float b){
  return (unsigned)f2bf(a) | ((unsigned)f2bf(b) << 16);
}
__device__ __forceinline__ float bflo(unsigned v){ return __uint_as_float(v << 16); }
__device__ __forceinline__ float bfhi(unsigned v){ return __uint_as_float(v & 0xffff0000u); }

// ---------------- CSR build ----------------
__global__ void k_count(const int* __restrict__ dst, unsigned* __restrict__ cnt){
  int i = blockIdx.x * 256 + threadIdx.x;
  if (i < NEDGE) atomicAdd(&cnt[dst[i]], 1u);
}

__global__ __launch_bounds__(1024) void k_scan(const unsigned* __restrict__ cnt,
                                               unsigned* __restrict__ rowptr,
                                               unsigned* __restrict__ cursor){
  __shared__ unsigned buf[1024];
  __shared__ unsigned carry;
  const int tid = threadIdx.x;
  if (tid == 0) carry = 0;
  __syncthreads();
  for (int base = 0; base < NNODE; base += 1024){
    int i = base + tid;
    unsigned v = (i < NNODE) ? cnt[i] : 0u;
    buf[tid] = v;
    __syncthreads();
    #pragma unroll
    for (int off = 1; off < 1024; off <<= 1){
      unsigned t = (tid >= off) ? buf[tid - off] : 0u;
      __syncthreads();
      buf[tid] += t;
      __syncthreads();
    }
    unsigned c = carry;
    unsigned incl = buf[tid];
    unsigned excl = incl - v;
    if (i < NNODE){ rowptr[i] = c + excl; cursor[i] = c + excl; }
    __syncthreads();
    if (tid == 1023) carry = c + incl;
    __syncthreads();
  }
  if (tid == 0) rowptr[NNODE] = carry;
}

__global__ void k_scatter(const int* __restrict__ src, const int* __restrict__ dst,
                          unsigned* __restrict__ cursor, unsigned* __restrict__ col){
  int i = blockIdx.x * 256 + threadIdx.x;
  if (i < NEDGE){
    int d = dst[i];
    unsigned p = atomicAdd(&cursor[d], 1u);
    col[p] = (unsigned)src[i];
  }
}

// ---------------- conversions ----------------
// x fp32 [N,128] -> bf16 into A1 columns 128..255 (A1 is [N,256] bf16)
__global__ void k_xcvt(const float* __restrict__ x, unsigned* __restrict__ A1u){
  int i = blockIdx.x * 256 + threadIdx.x;   // over N*32 float4s
  if (i >= NNODE * 32) return;
  float4 v = ((const float4*)x)[i];
  int e = i * 4;
  int row = e >> 7, c = e & 127;
  unsigned* d = A1u + (size_t)row * 128 + 64 + (c >> 1);
  d[0] = pk2(v.x, v.y);
  d[1] = pk2(v.z, v.w);
}

// Bwt1[n][k], n<256, k<256: k<128 -> W1_l[n][k], else W1_r[n][k-128]
__global__ void k_wcvt1(const float* __restrict__ W1l, const float* __restrict__ W1r,
                        unsigned short* __restrict__ Bwt1){
  int i = blockIdx.x * 256 + threadIdx.x;
  if (i >= 256 * 256) return;
  int n = i >> 8, k = i & 255;
  float v = (k < 128) ? W1l[n * 128 + k] : W1r[n * 128 + (k - 128)];
  Bwt1[i] = f2bf(v);
}

// Bwt2[n][k], n<128, k<256: n<64 -> W2_l[n][k], else W2_r[n-64][k]
__global__ void k_wcvt2(const float* __restrict__ W2l, const float* __restrict__ W2r,
                        unsigned short* __restrict__ Bwt2){
  int i = blockIdx.x * 256 + threadIdx.x;
  if (i >= 128 * 256) return;
  int n = i >> 8, k = i & 255;
  float v = (n < 64) ? W2l[n * 256 + k] : W2r[(n - 64) * 256 + k];
  Bwt2[i] = f2bf(v);
}

// ---------------- layer-1 aggregation: mean of x_bf16 over in-edges ----------------
// one 64-lane wave per node; lane holds 2 of 128 dims (one uint = bf16x2)
__global__ __launch_bounds__(256) void k_agg1(const unsigned* __restrict__ rowptr,
                                              const unsigned* __restrict__ col,
                                              unsigned* __restrict__ A1u){
  int gw = (blockIdx.x * 256 + threadIdx.x) >> 6;
  int lane = threadIdx.x & 63;
  if (gw >= NNODE) return;
  unsigned s0 = rowptr[gw], s1 = rowptr[gw + 1];
  float ax = 0.f, ay = 0.f;
  unsigned j = s0;
  for (; j + 1 < s1; j += 2){
    unsigned sa = col[j], sb = col[j + 1];
    unsigned va = A1u[(size_t)sa * 128 + 64 + lane];
    unsigned vb = A1u[(size_t)sb * 128 + 64 + lane];
    ax += bflo(va) + bflo(vb);
    ay += bfhi(va) + bfhi(vb);
  }
  if (j < s1){
    unsigned v = A1u[(size_t)col[j] * 128 + 64 + lane];
    ax += bflo(v); ay += bfhi(v);
  }
  float inv = 1.f / fmaxf((float)(s1 - s0), 1.f);
  A1u[(size_t)gw * 128 + lane] = pk2(ax * inv, ay * inv);
}

// ---------------- MFMA GEMM: C[nrows,BN] = A[nrows,256] * B^T, B stored [BN][256] ----------------
template<int BN, bool RELU, bool BIAS>
__global__ __launch_bounds__(256) void k_gemm(const unsigned short* __restrict__ A,
                                              const unsigned short* __restrict__ B,
                                              const float* __restrict__ bias,
                                              unsigned short* __restrict__ C,
                                              int nrows){
  constexpr int NF = BN / 64;              // 16-wide col-frags per wave
  __shared__ unsigned short a_t[64 * 64];  // [row][k] swizzled
  __shared__ unsigned short b_t[BN * 64];  // [n][k]   swizzled
  const int tid = threadIdx.x, wave = tid >> 6, lane = tid & 63;
  const int row0 = blockIdx.x * 64;
  char* ab = (char*)a_t;
  char* bb = (char*)b_t;

  f32x4 acc[4][NF];
  #pragma unroll
  for (int m = 0; m < 4; ++m)
    #pragma unroll
    for (int n = 0; n < NF; ++n)
      acc[m][n] = (f32x4){0.f, 0.f, 0.f, 0.f};

  for (int kt = 0; kt < 4; ++kt){
    { // stage A tile: 64 rows x 64 k
      int r = tid >> 2;
      int gr = row0 + r; if (gr > nrows - 1) gr = nrows - 1;
      const uint4* s4 = (const uint4*)(A + (size_t)gr * 256 + kt * 64);
      int c0 = (tid & 3) * 2;
      uint4 v0 = s4[c0], v1 = s4[c0 + 1];
      *(uint4*)(ab + r * 128 + ((c0 * 16) ^ ((r & 7) << 4))) = v0;
      *(uint4*)(ab + r * 128 + (((c0 + 1) * 16) ^ ((r & 7) << 4))) = v1;
    }
    { // stage B tile: BN n-rows x 64 k
      constexpr int CPT = BN / 32;         // 16B chunks per thread
      #pragma unroll
      for (int c = 0; c < CPT; ++c){
        int gc = tid * CPT + c;
        int n = gc >> 3, ck = gc & 7;
        uint4 v = ((const uint4*)(B + (size_t)n * 256 + kt * 64))[ck];
        *(uint4*)(bb + n * 128 + ((ck * 16) ^ ((n & 7) << 4))) = v;
      }
    }
    __syncthreads();
    #pragma unroll
    for (int kk = 0; kk < 2; ++kk){
      int k2 = (kk * 32 + ((lane >> 4) * 8)) * 2;   // byte offset of this lane's k-slice
      bf16x8 af[4];
      #pragma unroll
      for (int m = 0; m < 4; ++m){
        int rr = m * 16 + (lane & 15);
        af[m] = *(const bf16x8*)(ab + rr * 128 + (k2 ^ ((rr & 7) << 4)));
      }
      #pragma unroll
      for (int n = 0; n < NF; ++n){
        int cc = wave * (16 * NF) + n * 16 + (lane & 15);
        bf16x8 bfv = *(const bf16x8*)(bb + cc * 128 + (k2 ^ ((cc & 7) << 4)));
        #pragma unroll
        for (int m = 0; m < 4; ++m)
          acc[m][n] = __builtin_amdgcn_mfma_f32_16x16x32_bf16(af[m], bfv, acc[m][n], 0, 0, 0);
      }
    }
    __syncthreads();
  }
  // epilogue: C row = row0 + m*16 + (lane>>4)*4 + r ; col = wave*16*NF + n*16 + (lane&15)
  #pragma unroll
  for (int m = 0; m < 4; ++m){
    int rbase = row0 + m * 16 + ((lane >> 4) << 2);
    #pragma unroll
    for (int r = 0; r < 4; ++r){
      if (rbase + r < nrows){
        #pragma unroll
        for (int n = 0; n < NF; ++n){
          int cc = wave * (16 * NF) + n * 16 + (lane & 15);
          float v = acc[m][n][r];
          if (BIAS) v += bias[cc];
          if (RELU) v = fmaxf(v, 0.f);
          C[(size_t)(rbase + r) * BN + cc] = f2bf(v);
        }
      }
    }
  }
}

// ---------------- layer-2 aggregation + residual + bias ----------------
// 16 lanes per node, each lane 4 of 64 cols; zr is [N,128]: cols 0..63 = z, 64..127 = r
__global__ __launch_bounds__(256) void k_agg2(const unsigned* __restrict__ rowptr,
                                              const unsigned* __restrict__ col,
                                              const unsigned short* __restrict__ zr,
                                              const float* __restrict__ b2,
                                              float* __restrict__ out){
  int t = blockIdx.x * 256 + threadIdx.x;
  int node = t >> 4, gl = t & 15;
  if (node >= NNODE) return;
  unsigned s0 = rowptr[node], s1 = rowptr[node + 1];
  float a0 = 0.f, a1 = 0.f, a2 = 0.f, a3 = 0.f;
  unsigned j = s0;
  for (; j + 1 < s1; j += 2){
    unsigned sa = col[j], sb = col[j + 1];
    uint2 va = *(const uint2*)(zr + (size_t)sa * 128 + gl * 4);
    uint2 vb = *(const uint2*)(zr + (size_t)sb * 128 + gl * 4);
    a0 += bflo(va.x) + bflo(vb.x); a1 += bfhi(va.x) + bfhi(vb.x);
    a2 += bflo(va.y) + bflo(vb.y); a3 += bfhi(va.y) + bfhi(vb.y);
  }
  if (j < s1){
    uint2 v = *(const uint2*)(zr + (size_t)col[j] * 128 + gl * 4);
    a0 += bflo(v.x); a1 += bfhi(v.x); a2 += bflo(v.y); a3 += bfhi(v.y);
  }
  float inv = 1.f / fmaxf((float)(s1 - s0), 1.f);
  uint2 rv = *(const uint2*)(zr + (size_t)node * 128 + 64 + gl * 4);
  float4 res;
  res.x = a0 * inv + bflo(rv.x) + b2[gl * 4 + 0];
  res.y = a1 * inv + bfhi(rv.x) + b2[gl * 4 + 1];
  res.z = a2 * inv + bflo(rv.y) + b2[gl * 4 + 2];
  res.w = a3 * inv + bfhi(rv.y) + b2[gl * 4 + 3];
  ((float4*)out)[(size_t)node * 16 + gl] = res;
}

extern "C" void kernel_launch(void* const* d_in, const int* in_sizes, int n_in,
                              void* d_out, int out_size, void* d_ws, size_t ws_size,
                              hipStream_t stream) {
  const float* x   = (const float*)d_in[0];
  const int*   ei  = (const int*)d_in[1];
  const float* W1l = (const float*)d_in[2];
  const float* b1  = (const float*)d_in[3];
  const float* W1r = (const float*)d_in[4];
  const float* W2l = (const float*)d_in[5];
  const float* b2  = (const float*)d_in[6];
  const float* W2r = (const float*)d_in[7];
  float* out = (float*)d_out;

  char* ws = (char*)d_ws;
  size_t off = 0;
  auto alloc = [&](size_t bytes) -> void* {
    void* p = ws + off;
    off = (off + bytes + 255) & ~(size_t)255;
    return p;
  };
  unsigned* cnt    = (unsigned*)alloc((size_t)NNODE * 4);
  unsigned* rowptr = (unsigned*)alloc((size_t)(NNODE + 1) * 4);
  unsigned* cursor = (unsigned*)alloc((size_t)NNODE * 4);
  unsigned* col    = (unsigned*)alloc((size_t)NEDGE * 4);
  unsigned short* A1   = (unsigned short*)alloc((size_t)NNODE * 256 * 2);
  unsigned short* h    = (unsigned short*)alloc((size_t)NNODE * 256 * 2);
  unsigned short* zr   = (unsigned short*)alloc((size_t)NNODE * 128 * 2);
  unsigned short* Bwt1 = (unsigned short*)alloc(256 * 256 * 2);
  unsigned short* Bwt2 = (unsigned short*)alloc(128 * 256 * 2);

  const int* srcv = ei;
  const int* dstv = ei + NEDGE;

  hipMemsetAsync(cnt, 0, (size_t)NNODE * 4, stream);

  k_count<<<(NEDGE + 255) / 256, 256, 0, stream>>>(dstv, cnt);
  k_scan<<<1, 1024, 0, stream>>>(cnt, rowptr, cursor);
  k_scatter<<<(NEDGE + 255) / 256, 256, 0, stream>>>(srcv, dstv, cursor, col);

  k_xcvt<<<(NNODE * 32 + 255) / 256, 256, 0, stream>>>(x, (unsigned*)A1);
  k_wcvt1<<<256, 256, 0, stream>>>(W1l, W1r, Bwt1);
  k_wcvt2<<<128, 256, 0, stream>>>(W2l, W2r, Bwt2);

  k_agg1<<<(NNODE + 3) / 4, 256, 0, stream>>>(rowptr, col, (unsigned*)A1);

  int gblocks = (NNODE + 63) / 64;
  k_gemm<256, true,  true ><<<gblocks, 256, 0, stream>>>(A1, Bwt1, b1, h, NNODE);
  k_gemm<128, false, false><<<gblocks, 256, 0, stream>>>(h,  Bwt2, nullptr, zr, NNODE);

  k_agg2<<<(NNODE * 16 + 255) / 256, 256, 0, stream>>>(rowptr, col, zr, b2, out);
}

// Round 2
// 511.996 us; speedup vs baseline: 1.2979x; 1.2979x over previous
//
#include <hip/hip_runtime.h>
#include <hip/hip_bf16.h>

#define NNODE 100000
#define NEDGE 1600000
#define SBLK 1024
#define NBLK ((NNODE + SBLK - 1) / SBLK)   // 98

typedef __attribute__((ext_vector_type(8))) short bf16x8;
typedef __attribute__((ext_vector_type(4))) float f32x4;

__device__ __forceinline__ unsigned short f2bf(float f){
  unsigned u = __float_as_uint(f);
  u += 0x7fffu + ((u >> 16) & 1u);
  return (unsigned short)(u >> 16);
}
__device__ __forceinline__ unsigned pk2(float a, float b){
  return (unsigned)f2bf(a) | ((unsigned)f2bf(b) << 16);
}
__device__ __forceinline__ float bflo(unsigned v){ return __uint_as_float(v << 16); }
__device__ __forceinline__ float bfhi(unsigned v){ return __uint_as_float(v & 0xffff0000u); }

// ---------------- CSR build ----------------
__global__ void k_count(const int* __restrict__ dst, unsigned* __restrict__ cnt){
  int i = blockIdx.x * 256 + threadIdx.x;
  if (i < NEDGE) atomicAdd(&cnt[dst[i]], 1u);
}

// two-level parallel scan: (1) per-block sums
__global__ __launch_bounds__(1024) void k_blocksum(const unsigned* __restrict__ cnt,
                                                   unsigned* __restrict__ bsum){
  int i = blockIdx.x * SBLK + threadIdx.x;
  unsigned v = (i < NNODE) ? cnt[i] : 0u;
  #pragma unroll
  for (int off = 32; off; off >>= 1) v += __shfl_down(v, off, 64);
  __shared__ unsigned wsum[16];
  int lane = threadIdx.x & 63, wv = threadIdx.x >> 6;
  if (lane == 0) wsum[wv] = v;
  __syncthreads();
  if (wv == 0){
    unsigned t = (lane < 16) ? wsum[lane] : 0u;
    #pragma unroll
    for (int off = 8; off; off >>= 1) t += __shfl_down(t, off, 64);
    if (lane == 0) bsum[blockIdx.x] = t;
  }
}

// (2) exclusive-scan the 98 block sums in place
__global__ __launch_bounds__(128) void k_scanbsum(unsigned* __restrict__ bsum){
  __shared__ unsigned buf[128];
  int tid = threadIdx.x;
  unsigned v = (tid < NBLK) ? bsum[tid] : 0u;
  buf[tid] = v;
  __syncthreads();
  #pragma unroll
  for (int off = 1; off < 128; off <<= 1){
    unsigned t = (tid >= off) ? buf[tid - off] : 0u;
    __syncthreads();
    buf[tid] += t;
    __syncthreads();
  }
  if (tid < NBLK) bsum[tid] = buf[tid] - v;   // exclusive
}

// (3) per-block scan + apply offsets -> rowptr, cursor
__global__ __launch_bounds__(1024) void k_scanapply(const unsigned* __restrict__ cnt,
                                                    const unsigned* __restrict__ bsum,
                                                    unsigned* __restrict__ rowptr,
                                                    unsigned* __restrict__ cursor){
  int i = blockIdx.x * SBLK + threadIdx.x;
  unsigned v = (i < NNODE) ? cnt[i] : 0u;
  int lane = threadIdx.x & 63, wv = threadIdx.x >> 6;
  unsigned s = v;
  #pragma unroll
  for (int off = 1; off < 64; off <<= 1){
    unsigned t = __shfl_up(s, off, 64);
    if (lane >= off) s += t;
  }
  __shared__ unsigned wsum[16];
  if (lane == 63) wsum[wv] = s;
  __syncthreads();
  unsigned woff = 0;
  for (int w = 0; w < wv; ++w) woff += wsum[w];   // wave-uniform loop, LDS broadcast
  if (i < NNODE){
    unsigned excl = bsum[blockIdx.x] + woff + s - v;
    rowptr[i] = excl;
    cursor[i] = excl;
  }
  if (blockIdx.x == 0 && threadIdx.x == 0) rowptr[NNODE] = NEDGE;
}

__global__ void k_scatter(const int* __restrict__ src, const int* __restrict__ dst,
                          unsigned* __restrict__ cursor, unsigned* __restrict__ col){
  int i = blockIdx.x * 256 + threadIdx.x;
  if (i < NEDGE){
    int d = dst[i];
    unsigned p = atomicAdd(&cursor[d], 1u);
    col[p] = (unsigned)src[i];
  }
}

// ---------------- conversions ----------------
__global__ void k_xcvt(const float* __restrict__ x, unsigned* __restrict__ A1u){
  int i = blockIdx.x * 256 + threadIdx.x;   // over N*32 float4s
  if (i >= NNODE * 32) return;
  float4 v = ((const float4*)x)[i];
  int e = i * 4;
  int row = e >> 7, c = e & 127;
  unsigned* d = A1u + (size_t)row * 128 + 64 + (c >> 1);
  d[0] = pk2(v.x, v.y);
  d[1] = pk2(v.z, v.w);
}

__global__ void k_wcvt1(const float* __restrict__ W1l, const float* __restrict__ W1r,
                        unsigned short* __restrict__ Bwt1){
  int i = blockIdx.x * 256 + threadIdx.x;
  if (i >= 256 * 256) return;
  int n = i >> 8, k = i & 255;
  float v = (k < 128) ? W1l[n * 128 + k] : W1r[n * 128 + (k - 128)];
  Bwt1[i] = f2bf(v);
}

__global__ void k_wcvt2(const float* __restrict__ W2l, const float* __restrict__ W2r,
                        unsigned short* __restrict__ Bwt2){
  int i = blockIdx.x * 256 + threadIdx.x;
  if (i >= 128 * 256) return;
  int n = i >> 8, k = i & 255;
  float v = (n < 64) ? W2l[n * 256 + k] : W2r[(n - 64) * 256 + k];
  Bwt2[i] = f2bf(v);
}

// ---------------- layer-1 aggregation ----------------
__global__ __launch_bounds__(256) void k_agg1(const unsigned* __restrict__ rowptr,
                                              const unsigned* __restrict__ col,
                                              unsigned* __restrict__ A1u){
  int gw = (blockIdx.x * 256 + threadIdx.x) >> 6;
  int lane = threadIdx.x & 63;
  if (gw >= NNODE) return;
  unsigned s0 = rowptr[gw], s1 = rowptr[gw + 1];
  float ax = 0.f, ay = 0.f;
  unsigned j = s0;
  for (; j + 1 < s1; j += 2){
    unsigned sa = col[j], sb = col[j + 1];
    unsigned va = A1u[(size_t)sa * 128 + 64 + lane];
    unsigned vb = A1u[(size_t)sb * 128 + 64 + lane];
    ax += bflo(va) + bflo(vb);
    ay += bfhi(va) + bfhi(vb);
  }
  if (j < s1){
    unsigned v = A1u[(size_t)col[j] * 128 + 64 + lane];
    ax += bflo(v); ay += bfhi(v);
  }
  float inv = 1.f / fmaxf((float)(s1 - s0), 1.f);
  A1u[(size_t)gw * 128 + lane] = pk2(ax * inv, ay * inv);
}

// ---------------- MFMA GEMM ----------------
template<int BN, bool RELU, bool BIAS>
__global__ __launch_bounds__(256) void k_gemm(const unsigned short* __restrict__ A,
                                              const unsigned short* __restrict__ B,
                                              const float* __restrict__ bias,
                                              unsigned short* __restrict__ C,
                                              int nrows){
  constexpr int NF = BN / 64;
  __shared__ unsigned short a_t[64 * 64];
  __shared__ unsigned short b_t[BN * 64];
  const int tid = threadIdx.x, wave = tid >> 6, lane = tid & 63;
  const int row0 = blockIdx.x * 64;
  char* ab = (char*)a_t;
  char* bb = (char*)b_t;

  f32x4 acc[4][NF];
  #pragma unroll
  for (int m = 0; m < 4; ++m)
    #pragma unroll
    for (int n = 0; n < NF; ++n)
      acc[m][n] = (f32x4){0.f, 0.f, 0.f, 0.f};

  for (int kt = 0; kt < 4; ++kt){
    {
      int r = tid >> 2;
      int gr = row0 + r; if (gr > nrows - 1) gr = nrows - 1;
      const uint4* s4 = (const uint4*)(A + (size_t)gr * 256 + kt * 64);
      int c0 = (tid & 3) * 2;
      uint4 v0 = s4[c0], v1 = s4[c0 + 1];
      *(uint4*)(ab + r * 128 + ((c0 * 16) ^ ((r & 7) << 4))) = v0;
      *(uint4*)(ab + r * 128 + (((c0 + 1) * 16) ^ ((r & 7) << 4))) = v1;
    }
    {
      constexpr int CPT = BN / 32;
      #pragma unroll
      for (int c = 0; c < CPT; ++c){
        int gc = tid * CPT + c;
        int n = gc >> 3, ck = gc & 7;
        uint4 v = ((const uint4*)(B + (size_t)n * 256 + kt * 64))[ck];
        *(uint4*)(bb + n * 128 + ((ck * 16) ^ ((n & 7) << 4))) = v;
      }
    }
    __syncthreads();
    #pragma unroll
    for (int kk = 0; kk < 2; ++kk){
      int k2 = (kk * 32 + ((lane >> 4) * 8)) * 2;
      bf16x8 af[4];
      #pragma unroll
      for (int m = 0; m < 4; ++m){
        int rr = m * 16 + (lane & 15);
        af[m] = *(const bf16x8*)(ab + rr * 128 + (k2 ^ ((rr & 7) << 4)));
      }
      #pragma unroll
      for (int n = 0; n < NF; ++n){
        int cc = wave * (16 * NF) + n * 16 + (lane & 15);
        bf16x8 bfv = *(const bf16x8*)(bb + cc * 128 + (k2 ^ ((cc & 7) << 4)));
        #pragma unroll
        for (int m = 0; m < 4; ++m)
          acc[m][n] = __builtin_amdgcn_mfma_f32_16x16x32_bf16(af[m], bfv, acc[m][n], 0, 0, 0);
      }
    }
    __syncthreads();
  }
  #pragma unroll
  for (int m = 0; m < 4; ++m){
    int rbase = row0 + m * 16 + ((lane >> 4) << 2);
    #pragma unroll
    for (int r = 0; r < 4; ++r){
      if (rbase + r < nrows){
        #pragma unroll
        for (int n = 0; n < NF; ++n){
          int cc = wave * (16 * NF) + n * 16 + (lane & 15);
          float v = acc[m][n][r];
          if (BIAS) v += bias[cc];
          if (RELU) v = fmaxf(v, 0.f);
          C[(size_t)(rbase + r) * BN + cc] = f2bf(v);
        }
      }
    }
  }
}

// ---------------- layer-2 aggregation + residual + bias ----------------
__global__ __launch_bounds__(256) void k_agg2(const unsigned* __restrict__ rowptr,
                                              const unsigned* __restrict__ col,
                                              const unsigned short* __restrict__ zr,
                                              const float* __restrict__ b2,
                                              float* __restrict__ out){
  int t = blockIdx.x * 256 + threadIdx.x;
  int node = t >> 4, gl = t & 15;
  if (node >= NNODE) return;
  unsigned s0 = rowptr[node], s1 = rowptr[node + 1];
  float a0 = 0.f, a1 = 0.f, a2 = 0.f, a3 = 0.f;
  unsigned j = s0;
  for (; j + 1 < s1; j += 2){
    unsigned sa = col[j], sb = col[j + 1];
    uint2 va = *(const uint2*)(zr + (size_t)sa * 128 + gl * 4);
    uint2 vb = *(const uint2*)(zr + (size_t)sb * 128 + gl * 4);
    a0 += bflo(va.x) + bflo(vb.x); a1 += bfhi(va.x) + bfhi(vb.x);
    a2 += bflo(va.y) + bflo(vb.y); a3 += bfhi(va.y) + bfhi(vb.y);
  }
  if (j < s1){
    uint2 v = *(const uint2*)(zr + (size_t)col[j] * 128 + gl * 4);
    a0 += bflo(v.x); a1 += bfhi(v.x); a2 += bflo(v.y); a3 += bfhi(v.y);
  }
  float inv = 1.f / fmaxf((float)(s1 - s0), 1.f);
  uint2 rv = *(const uint2*)(zr + (size_t)node * 128 + 64 + gl * 4);
  float4 res;
  res.x = a0 * inv + bflo(rv.x) + b2[gl * 4 + 0];
  res.y = a1 * inv + bfhi(rv.x) + b2[gl * 4 + 1];
  res.z = a2 * inv + bflo(rv.y) + b2[gl * 4 + 2];
  res.w = a3 * inv + bfhi(rv.y) + b2[gl * 4 + 3];
  ((float4*)out)[(size_t)node * 16 + gl] = res;
}

extern "C" void kernel_launch(void* const* d_in, const int* in_sizes, int n_in,
                              void* d_out, int out_size, void* d_ws, size_t ws_size,
                              hipStream_t stream) {
  const float* x   = (const float*)d_in[0];
  const int*   ei  = (const int*)d_in[1];
  const float* W1l = (const float*)d_in[2];
  const float* b1  = (const float*)d_in[3];
  const float* W1r = (const float*)d_in[4];
  const float* W2l = (const float*)d_in[5];
  const float* b2  = (const float*)d_in[6];
  const float* W2r = (const float*)d_in[7];
  float* out = (float*)d_out;

  char* ws = (char*)d_ws;
  size_t off = 0;
  auto alloc = [&](size_t bytes) -> void* {
    void* p = ws + off;
    off = (off + bytes + 255) & ~(size_t)255;
    return p;
  };
  unsigned* cnt    = (unsigned*)alloc((size_t)NNODE * 4);
  unsigned* rowptr = (unsigned*)alloc((size_t)(NNODE + 1) * 4);
  unsigned* cursor = (unsigned*)alloc((size_t)NNODE * 4);
  unsigned* col    = (unsigned*)alloc((size_t)NEDGE * 4);
  unsigned* bsum   = (unsigned*)alloc((size_t)NBLK * 4);
  unsigned short* A1   = (unsigned short*)alloc((size_t)NNODE * 256 * 2);
  unsigned short* h    = (unsigned short*)alloc((size_t)NNODE * 256 * 2);
  unsigned short* zr   = (unsigned short*)alloc((size_t)NNODE * 128 * 2);
  unsigned short* Bwt1 = (unsigned short*)alloc(256 * 256 * 2);
  unsigned short* Bwt2 = (unsigned short*)alloc(128 * 256 * 2);

  const int* srcv = ei;
  const int* dstv = ei + NEDGE;

  hipMemsetAsync(cnt, 0, (size_t)NNODE * 4, stream);

  k_count<<<(NEDGE + 255) / 256, 256, 0, stream>>>(dstv, cnt);
  k_blocksum<<<NBLK, 1024, 0, stream>>>(cnt, bsum);
  k_scanbsum<<<1, 128, 0, stream>>>(bsum);
  k_scanapply<<<NBLK, 1024, 0, stream>>>(cnt, bsum, rowptr, cursor);
  k_scatter<<<(NEDGE + 255) / 256, 256, 0, stream>>>(srcv, dstv, cursor, col);

  k_xcvt<<<(NNODE * 32 + 255) / 256, 256, 0, stream>>>(x, (unsigned*)A1);
  k_wcvt1<<<256, 256, 0, stream>>>(W1l, W1r, Bwt1);
  k_wcvt2<<<128, 256, 0, stream>>>(W2l, W2r, Bwt2);

  k_agg1<<<(NNODE + 3) / 4, 256, 0, stream>>>(rowptr, col, (unsigned*)A1);

  int gblocks = (NNODE + 63) / 64;
  k_gemm<256, true,  true ><<<gblocks, 256, 0, stream>>>(A1, Bwt1, b1, h, NNODE);
  k_gemm<128, false, false><<<gblocks, 256, 0, stream>>>(h,  Bwt2, nullptr, zr, NNODE);

  k_agg2<<<(NNODE * 16 + 255) / 256, 256, 0, stream>>>(rowptr, col, zr, b2, out);
}